// Round 4
// baseline (461.119 us; speedup 1.0000x reference)
//
#include <hip/hip_runtime.h>
#include <hip/hip_bf16.h>
#include <cstdint>
#include <cstddef>

// GATv2Conv forward, N=100000, E=1.6M, IN=128, H=4, C=32 (H*C=128).
//
// Pipeline:
//   1) gemm2_k : fused  x@W_l -> xl , x@W_r -> xr  (fp32 math, bf16 stores)
//   2) counting-sort edges by dst: hist -> scanA -> scanB -> scanC -> scatter
//      (scatter XCD-range-partitioned to kill write amplification)
//   3) agg_k   : one wave per dst node; 2 edges/iteration (one per 32-lane half,
//                4 channels per lane); softmax WITHOUT max-subtraction (logits
//                are ~N(0,1.4), |p|max ~ 8 << 88, fp32-exp safe), so 1 exp per
//                2 edges and 3 shfl per 2 edges. No serial softmax dependency.

#define NEG_SLOPE 0.2f
#define EPS_F 1e-16f

static __device__ __forceinline__ unsigned f2bf(float f) {
    unsigned u = __float_as_uint(f);
    return (u + 0x7fffu + ((u >> 16) & 1u)) >> 16;   // RNE
}
static __device__ __forceinline__ float bf2f(unsigned h) {
    return __uint_as_float(h << 16);
}

// ------------- fused GEMM: xl = A*Wl, xr = A*Wr ; A[nrows x 128], W[128 x 128] -------------
__global__ __launch_bounds__(256) void gemm2_k(const float* __restrict__ A,
                                               const float* __restrict__ Wl,
                                               const float* __restrict__ Wr,
                                               unsigned* __restrict__ xlb,
                                               unsigned* __restrict__ xrb, int nrows) {
    __shared__ float xs[64][36];    // 64 rows x 32 k (+4 pad)
    __shared__ float wls[32][128];
    __shared__ float wrs[32][128];

    const int tid = threadIdx.x;
    const int ty = tid >> 4;   // 0..15 -> 4 rows
    const int tx = tid & 15;   // 0..15 -> cols tx*4..+3 and 64+tx*4..+3
    const int row0 = blockIdx.x * 64;

    float accl[4][8], accr[4][8];
#pragma unroll
    for (int i = 0; i < 4; ++i)
#pragma unroll
        for (int j = 0; j < 8; ++j) { accl[i][j] = 0.f; accr[i][j] = 0.f; }

    for (int kc = 0; kc < 4; ++kc) {
#pragma unroll
        for (int i = 0; i < 2; ++i) {
            int idx = tid + i * 256;
            int r = idx >> 3, kq = idx & 7;
            int gr = row0 + r;
            gr = gr < nrows ? gr : nrows - 1;
            *(float4*)(&xs[r][kq * 4]) = *(const float4*)(A + (size_t)gr * 128 + kc * 32 + kq * 4);
        }
#pragma unroll
        for (int i = 0; i < 4; ++i) {
            int idx = tid + i * 256;
            int k = idx >> 5, c4 = idx & 31;
            *(float4*)(&wls[k][c4 * 4]) = *(const float4*)(Wl + (size_t)(kc * 32 + k) * 128 + c4 * 4);
            *(float4*)(&wrs[k][c4 * 4]) = *(const float4*)(Wr + (size_t)(kc * 32 + k) * 128 + c4 * 4);
        }
        __syncthreads();

#pragma unroll 8
        for (int k = 0; k < 32; ++k) {
            float av[4];
            av[0] = xs[ty * 4 + 0][k];
            av[1] = xs[ty * 4 + 1][k];
            av[2] = xs[ty * 4 + 2][k];
            av[3] = xs[ty * 4 + 3][k];
            float4 l0 = *(float4*)(&wls[k][tx * 4]);
            float4 l1 = *(float4*)(&wls[k][64 + tx * 4]);
            float4 r0 = *(float4*)(&wrs[k][tx * 4]);
            float4 r1 = *(float4*)(&wrs[k][64 + tx * 4]);
            float lw[8] = {l0.x, l0.y, l0.z, l0.w, l1.x, l1.y, l1.z, l1.w};
            float rw[8] = {r0.x, r0.y, r0.z, r0.w, r1.x, r1.y, r1.z, r1.w};
#pragma unroll
            for (int i = 0; i < 4; ++i)
#pragma unroll
                for (int j = 0; j < 8; ++j) {
                    accl[i][j] = fmaf(av[i], lw[j], accl[i][j]);
                    accr[i][j] = fmaf(av[i], rw[j], accr[i][j]);
                }
        }
        __syncthreads();
    }

#pragma unroll
    for (int i = 0; i < 4; ++i) {
        int gr = row0 + ty * 4 + i;
        if (gr < nrows) {
            uint2 la = {f2bf(accl[i][0]) | (f2bf(accl[i][1]) << 16),
                        f2bf(accl[i][2]) | (f2bf(accl[i][3]) << 16)};
            uint2 lb = {f2bf(accl[i][4]) | (f2bf(accl[i][5]) << 16),
                        f2bf(accl[i][6]) | (f2bf(accl[i][7]) << 16)};
            uint2 ra = {f2bf(accr[i][0]) | (f2bf(accr[i][1]) << 16),
                        f2bf(accr[i][2]) | (f2bf(accr[i][3]) << 16)};
            uint2 rb = {f2bf(accr[i][4]) | (f2bf(accr[i][5]) << 16),
                        f2bf(accr[i][6]) | (f2bf(accr[i][7]) << 16)};
            *(uint2*)(xlb + (size_t)gr * 64 + tx * 2) = la;
            *(uint2*)(xlb + (size_t)gr * 64 + 32 + tx * 2) = lb;
            *(uint2*)(xrb + (size_t)gr * 64 + tx * 2) = ra;
            *(uint2*)(xrb + (size_t)gr * 64 + 32 + tx * 2) = rb;
        }
    }
}

// ---------------- counting sort of edges by dst (parallel 2-level scan) ----------------
__global__ void hist_k(const int* __restrict__ dst, int E, int* __restrict__ cnt) {
    int e = blockIdx.x * blockDim.x + threadIdx.x;
    if (e < E) atomicAdd(&cnt[dst[e]], 1);
}

#define SCAN_B 256
__global__ __launch_bounds__(SCAN_B) void scanA_k(const int* __restrict__ cnt, int n,
                                                  int* __restrict__ row_start,
                                                  int* __restrict__ bsum) {
    const int tid = threadIdx.x, lane = tid & 63, wid = tid >> 6;
    const int g = blockIdx.x * SCAN_B + tid;
    int v = (g < n) ? cnt[g] : 0;
    int inc = v;
#pragma unroll
    for (int d = 1; d < 64; d <<= 1) {
        int t = __shfl_up(inc, d);
        if (lane >= d) inc += t;
    }
    __shared__ int wsum[SCAN_B / 64];
    if (lane == 63) wsum[wid] = inc;
    __syncthreads();
    int add = 0;
    for (int w = 0; w < wid; ++w) add += wsum[w];
    inc += add;
    if (g < n) row_start[g] = inc - v;
    if (tid == SCAN_B - 1) bsum[blockIdx.x] = inc;
}

__global__ __launch_bounds__(512) void scanB_k(int* __restrict__ bsum, int nb) {
    const int tid = threadIdx.x, lane = tid & 63, wid = tid >> 6;
    int v = (tid < nb) ? bsum[tid] : 0;
    int inc = v;
#pragma unroll
    for (int d = 1; d < 64; d <<= 1) {
        int t = __shfl_up(inc, d);
        if (lane >= d) inc += t;
    }
    __shared__ int wsum[8];
    if (lane == 63) wsum[wid] = inc;
    __syncthreads();
    int add = 0;
    for (int w = 0; w < wid; ++w) add += wsum[w];
    inc += add;
    if (tid < nb) bsum[tid] = inc - v;
}

__global__ __launch_bounds__(SCAN_B) void scanC_k(int* __restrict__ row_start,
                                                  const int* __restrict__ bsum,
                                                  int* __restrict__ cursor, int n, int E) {
    const int g = blockIdx.x * SCAN_B + threadIdx.x;
    if (g < n) {
        int v = row_start[g] + bsum[blockIdx.x];
        row_start[g] = v;
        cursor[g] = v;
    }
    if (g == 0) row_start[n] = E;
}

// XCD-range-partitioned scatter (see R2 notes): one XCD owns each dst-range's lines.
#define NRANGE 8
__global__ __launch_bounds__(256) void scatter_k(const int* __restrict__ src,
                                                 const int* __restrict__ dst, int E,
                                                 int rsz, int chunk_e,
                                                 int* __restrict__ cursor,
                                                 int* __restrict__ src_sorted) {
    const int r = blockIdx.x & (NRANGE - 1);
    const int c = blockIdx.x >> 3;
    const unsigned r_lo = (unsigned)(r * rsz);
    const int e0 = c * chunk_e;
    const int e1 = min(e0 + chunk_e, E);
    for (int e = e0 + (int)threadIdx.x; e < e1; e += 256) {
        int d = dst[e];
        if ((unsigned)d - r_lo < (unsigned)rsz) {
            int pos = atomicAdd(&cursor[d], 1);
            src_sorted[pos] = src[e];
        }
    }
}

// ---------------- aggregation: one wave per dst node, 2 edges per iteration ----------------
// lane = 32*half + idx; idx=0..31 covers channels idx*4..idx*4+3 (head = idx>>3).
// Per pair of edges: gather uint2 (4 bf16) per lane, dot over 8 lanes (3 shfl),
// w = exp(p) (no max subtraction -- logits are small), accumulate l/A[4].
__global__ __launch_bounds__(256) void agg_k(const unsigned* __restrict__ xlb,
                                             const unsigned* __restrict__ xrb,
                                             const float* __restrict__ att,
                                             const float* __restrict__ bias,
                                             const int* __restrict__ row_start,
                                             const int* __restrict__ src_sorted,
                                             int n, float* __restrict__ out) {
    const int wave = threadIdx.x >> 6;
    const int lane = threadIdx.x & 63;
    const int i = blockIdx.x * 4 + wave;
    if (i >= n) return;

    const int idx  = lane & 31;   // channel group (4 channels)
    const int half = lane >> 5;   // which edge of the pair

    uint2 xr2 = *(const uint2*)(xrb + (size_t)i * 64 + idx * 2);
    float xr0 = bf2f(xr2.x & 0xffffu), xr1 = bf2f(xr2.x >> 16);
    float xr2f = bf2f(xr2.y & 0xffffu), xr3 = bf2f(xr2.y >> 16);
    float4 at4 = *(const float4*)(att + idx * 4);

    const int k0 = row_start[i];
    const int k1 = row_start[i + 1];

    float l = 0.f, A0 = 0.f, A1 = 0.f, A2 = 0.f, A3 = 0.f;

#pragma unroll 2
    for (int k = k0; k < k1; k += 2) {
        int kk = k + half;
        bool valid = kk < k1;
        int s = src_sorted[valid ? kk : k0];
        uint2 v = *(const uint2*)(xlb + (size_t)s * 64 + idx * 2);
        float x0 = bf2f(v.x & 0xffffu), x1 = bf2f(v.x >> 16);
        float x2 = bf2f(v.y & 0xffffu), x3 = bf2f(v.y >> 16);
        float h0 = x0 + xr0, h1 = x1 + xr1, h2 = x2 + xr2f, h3 = x3 + xr3;
        h0 = fmaxf(h0, NEG_SLOPE * h0);
        h1 = fmaxf(h1, NEG_SLOPE * h1);
        h2 = fmaxf(h2, NEG_SLOPE * h2);
        h3 = fmaxf(h3, NEG_SLOPE * h3);
        float p = fmaf(at4.x, h0, at4.y * h1) + fmaf(at4.z, h2, at4.w * h3);
        // reduce over the 8 lanes of this (edge, head) group
        p += __shfl_xor(p, 1);
        p += __shfl_xor(p, 2);
        p += __shfl_xor(p, 4);
        float w = valid ? __expf(p) : 0.f;
        l += w;
        A0 = fmaf(w, x0, A0);
        A1 = fmaf(w, x1, A1);
        A2 = fmaf(w, x2, A2);
        A3 = fmaf(w, x3, A3);
    }

    // merge the two halves (once per node)
    l  += __shfl_xor(l, 32);
    A0 += __shfl_xor(A0, 32);
    A1 += __shfl_xor(A1, 32);
    A2 += __shfl_xor(A2, 32);
    A3 += __shfl_xor(A3, 32);

    if (half == 0) {
        float inv = 1.f / (l + EPS_F);
        float4 b4 = *(const float4*)(bias + idx * 4);
        float4 o = {fmaf(A0, inv, b4.x), fmaf(A1, inv, b4.y),
                    fmaf(A2, inv, b4.z), fmaf(A3, inv, b4.w)};
        *(float4*)(out + (size_t)i * 128 + idx * 4) = o;
    }
}

// ---------------- launch ----------------
extern "C" void kernel_launch(void* const* d_in, const int* in_sizes, int n_in,
                              void* d_out, int out_size, void* d_ws, size_t ws_size,
                              hipStream_t stream) {
    const float* x    = (const float*)d_in[0];
    const int*   ei   = (const int*)d_in[1];
    const float* W_l  = (const float*)d_in[2];
    const float* W_r  = (const float*)d_in[3];
    const float* att  = (const float*)d_in[4];
    const float* bias = (const float*)d_in[5];
    float* out = (float*)d_out;

    const int N = in_sizes[0] / 128;
    const int E = in_sizes[1] / 2;
    const int* src = ei;
    const int* dst = ei + E;

    char* ws = (char*)d_ws;
    size_t off = 0;
    auto alloc = [&](size_t bytes) {
        void* p = ws + off;
        off += (bytes + 15) & ~(size_t)15;
        return p;
    };
    unsigned* xlb     = (unsigned*)alloc((size_t)N * 64 * 4);   // bf16-packed
    unsigned* xrb     = (unsigned*)alloc((size_t)N * 64 * 4);
    int* cnt          = (int*)alloc((size_t)N * 4);
    int* row_start    = (int*)alloc((size_t)(N + 1) * 4);
    int* cursor       = (int*)alloc((size_t)N * 4);
    const int nsb = (N + SCAN_B - 1) / SCAN_B;
    int* bsum         = (int*)alloc((size_t)nsb * 4);
    int* src_sorted   = (int*)alloc((size_t)E * 4);
    (void)ws_size;

    hipMemsetAsync(cnt, 0, (size_t)N * 4, stream);

    gemm2_k<<<(N + 63) / 64, 256, 0, stream>>>(x, W_l, W_r, xlb, xrb, N);

    hist_k<<<(E + 255) / 256, 256, 0, stream>>>(dst, E, cnt);
    scanA_k<<<nsb, SCAN_B, 0, stream>>>(cnt, N, row_start, bsum);
    scanB_k<<<1, 512, 0, stream>>>(bsum, nsb);
    scanC_k<<<nsb, SCAN_B, 0, stream>>>(row_start, bsum, cursor, N, E);

    const int rsz = (N + NRANGE - 1) / NRANGE;
    const int nchunks = 128;
    const int chunk_e = (E + nchunks - 1) / nchunks;
    scatter_k<<<NRANGE * nchunks, 256, 0, stream>>>(src, dst, E, rsz, chunk_e,
                                                    cursor, src_sorted);

    agg_k<<<(N + 3) / 4, 256, 0, stream>>>(xlb, xrb, att, bias, row_start, src_sorted, N, out);
}

// Round 5
// 399.724 us; speedup vs baseline: 1.1536x; 1.1536x over previous
//
#include <hip/hip_runtime.h>
#include <hip/hip_bf16.h>
#include <cstdint>
#include <cstddef>

// GATv2Conv forward, N=100000, E=1.6M, IN=128, H=4, C=32 (H*C=128).
//
// Pipeline:
//   1) gemm_hist_k : blocks [0,nHist) = XCD-range-partitioned histogram of dst
//                    (all atomics for a cnt-line from ONE XCD -> no L2 ping-pong);
//                    blocks [nHist,..) = fused GEMM x@W_l -> xl, x@W_r -> xr
//                    (fp32 math, bf16 stores). Atomic-bound + VALU-bound co-schedule.
//   2) scanA/B/C   : 2-level exclusive scan of cnt -> row_start, cursor; zero-pads
//                    src_sorted[E..E+8).
//   3) scatter_k   : XCD-range-partitioned counting-sort scatter (R2 win).
//   4) agg_k       : one wave per dst node, 8 edges/iteration (4 per 32-lane half),
//                    4 gathers in flight -> line-request ILP; softmax without
//                    max-subtraction (logits ~N(0,1.4), fp32 exp safe).

#define NEG_SLOPE 0.2f
#define EPS_F 1e-16f
#define NRANGE 8

static __device__ __forceinline__ unsigned f2bf(float f) {
    unsigned u = __float_as_uint(f);
    return (u + 0x7fffu + ((u >> 16) & 1u)) >> 16;   // RNE
}
static __device__ __forceinline__ float bf2f(unsigned h) {
    return __uint_as_float(h << 16);
}

// ------------- fused hist + GEMM -------------
// Hist blocks FIRST (r = blockIdx.x & 7 keeps range<->XCD affinity on the
// round-robin dispatch), GEMM blocks after.
__global__ __launch_bounds__(256) void gemm_hist_k(const float* __restrict__ A,
                                                   const float* __restrict__ Wl,
                                                   const float* __restrict__ Wr,
                                                   unsigned* __restrict__ xlb,
                                                   unsigned* __restrict__ xrb, int nrows,
                                                   const int* __restrict__ dst, int E,
                                                   int rsz, int chunk_e, int nHist,
                                                   int* __restrict__ cnt) {
    __shared__ float xs[64][36];
    __shared__ float wls[32][128];
    __shared__ float wrs[32][128];

    if (blockIdx.x < (unsigned)nHist) {
        // ---- histogram part ----
        const int r = blockIdx.x & (NRANGE - 1);
        const int c = blockIdx.x >> 3;
        const unsigned r_lo = (unsigned)(r * rsz);
        const int e0 = c * chunk_e;
        const int e1 = min(e0 + chunk_e, E);
        for (int e = e0 + (int)threadIdx.x; e < e1; e += 256) {
            int d = dst[e];
            if ((unsigned)d - r_lo < (unsigned)rsz) atomicAdd(&cnt[d], 1);
        }
        return;
    }

    // ---- GEMM part ----
    const int tid = threadIdx.x;
    const int ty = tid >> 4;
    const int tx = tid & 15;
    const int row0 = (blockIdx.x - nHist) * 64;

    float accl[4][8], accr[4][8];
#pragma unroll
    for (int i = 0; i < 4; ++i)
#pragma unroll
        for (int j = 0; j < 8; ++j) { accl[i][j] = 0.f; accr[i][j] = 0.f; }

    for (int kc = 0; kc < 4; ++kc) {
#pragma unroll
        for (int i = 0; i < 2; ++i) {
            int idx = tid + i * 256;
            int rr = idx >> 3, kq = idx & 7;
            int gr = row0 + rr;
            gr = gr < nrows ? gr : nrows - 1;
            *(float4*)(&xs[rr][kq * 4]) = *(const float4*)(A + (size_t)gr * 128 + kc * 32 + kq * 4);
        }
#pragma unroll
        for (int i = 0; i < 4; ++i) {
            int idx = tid + i * 256;
            int k = idx >> 5, c4 = idx & 31;
            *(float4*)(&wls[k][c4 * 4]) = *(const float4*)(Wl + (size_t)(kc * 32 + k) * 128 + c4 * 4);
            *(float4*)(&wrs[k][c4 * 4]) = *(const float4*)(Wr + (size_t)(kc * 32 + k) * 128 + c4 * 4);
        }
        __syncthreads();

#pragma unroll 8
        for (int k = 0; k < 32; ++k) {
            float av[4];
            av[0] = xs[ty * 4 + 0][k];
            av[1] = xs[ty * 4 + 1][k];
            av[2] = xs[ty * 4 + 2][k];
            av[3] = xs[ty * 4 + 3][k];
            float4 l0 = *(float4*)(&wls[k][tx * 4]);
            float4 l1 = *(float4*)(&wls[k][64 + tx * 4]);
            float4 r0 = *(float4*)(&wrs[k][tx * 4]);
            float4 r1 = *(float4*)(&wrs[k][64 + tx * 4]);
            float lw[8] = {l0.x, l0.y, l0.z, l0.w, l1.x, l1.y, l1.z, l1.w};
            float rw[8] = {r0.x, r0.y, r0.z, r0.w, r1.x, r1.y, r1.z, r1.w};
#pragma unroll
            for (int i = 0; i < 4; ++i)
#pragma unroll
                for (int j = 0; j < 8; ++j) {
                    accl[i][j] = fmaf(av[i], lw[j], accl[i][j]);
                    accr[i][j] = fmaf(av[i], rw[j], accr[i][j]);
                }
        }
        __syncthreads();
    }

#pragma unroll
    for (int i = 0; i < 4; ++i) {
        int gr = row0 + ty * 4 + i;
        if (gr < nrows) {
            uint2 la = {f2bf(accl[i][0]) | (f2bf(accl[i][1]) << 16),
                        f2bf(accl[i][2]) | (f2bf(accl[i][3]) << 16)};
            uint2 lb = {f2bf(accl[i][4]) | (f2bf(accl[i][5]) << 16),
                        f2bf(accl[i][6]) | (f2bf(accl[i][7]) << 16)};
            uint2 ra = {f2bf(accr[i][0]) | (f2bf(accr[i][1]) << 16),
                        f2bf(accr[i][2]) | (f2bf(accr[i][3]) << 16)};
            uint2 rb = {f2bf(accr[i][4]) | (f2bf(accr[i][5]) << 16),
                        f2bf(accr[i][6]) | (f2bf(accr[i][7]) << 16)};
            *(uint2*)(xlb + (size_t)gr * 64 + tx * 2) = la;
            *(uint2*)(xlb + (size_t)gr * 64 + 32 + tx * 2) = lb;
            *(uint2*)(xrb + (size_t)gr * 64 + tx * 2) = ra;
            *(uint2*)(xrb + (size_t)gr * 64 + 32 + tx * 2) = rb;
        }
    }
}

// ---------------- 2-level scan ----------------
#define SCAN_B 256
__global__ __launch_bounds__(SCAN_B) void scanA_k(const int* __restrict__ cnt, int n,
                                                  int* __restrict__ row_start,
                                                  int* __restrict__ bsum) {
    const int tid = threadIdx.x, lane = tid & 63, wid = tid >> 6;
    const int g = blockIdx.x * SCAN_B + tid;
    int v = (g < n) ? cnt[g] : 0;
    int inc = v;
#pragma unroll
    for (int d = 1; d < 64; d <<= 1) {
        int t = __shfl_up(inc, d);
        if (lane >= d) inc += t;
    }
    __shared__ int wsum[SCAN_B / 64];
    if (lane == 63) wsum[wid] = inc;
    __syncthreads();
    int add = 0;
    for (int w = 0; w < wid; ++w) add += wsum[w];
    inc += add;
    if (g < n) row_start[g] = inc - v;
    if (tid == SCAN_B - 1) bsum[blockIdx.x] = inc;
}

__global__ __launch_bounds__(512) void scanB_k(int* __restrict__ bsum, int nb) {
    const int tid = threadIdx.x, lane = tid & 63, wid = tid >> 6;
    int v = (tid < nb) ? bsum[tid] : 0;
    int inc = v;
#pragma unroll
    for (int d = 1; d < 64; d <<= 1) {
        int t = __shfl_up(inc, d);
        if (lane >= d) inc += t;
    }
    __shared__ int wsum[8];
    if (lane == 63) wsum[wid] = inc;
    __syncthreads();
    int add = 0;
    for (int w = 0; w < wid; ++w) add += wsum[w];
    inc += add;
    if (tid < nb) bsum[tid] = inc - v;
}

__global__ __launch_bounds__(SCAN_B) void scanC_k(int* __restrict__ row_start,
                                                  const int* __restrict__ bsum,
                                                  int* __restrict__ cursor, int n, int E,
                                                  int* __restrict__ src_sorted) {
    const int g = blockIdx.x * SCAN_B + threadIdx.x;
    if (g < n) {
        int v = row_start[g] + bsum[blockIdx.x];
        row_start[g] = v;
        cursor[g] = v;
    }
    if (g == 0) row_start[n] = E;
    if (blockIdx.x == 0 && threadIdx.x < 8) src_sorted[E + threadIdx.x] = 0;  // pad for agg int4-ish reads
}

// XCD-range-partitioned scatter.
__global__ __launch_bounds__(256) void scatter_k(const int* __restrict__ src,
                                                 const int* __restrict__ dst, int E,
                                                 int rsz, int chunk_e,
                                                 int* __restrict__ cursor,
                                                 int* __restrict__ src_sorted) {
    const int r = blockIdx.x & (NRANGE - 1);
    const int c = blockIdx.x >> 3;
    const unsigned r_lo = (unsigned)(r * rsz);
    const int e0 = c * chunk_e;
    const int e1 = min(e0 + chunk_e, E);
    for (int e = e0 + (int)threadIdx.x; e < e1; e += 256) {
        int d = dst[e];
        if ((unsigned)d - r_lo < (unsigned)rsz) {
            int pos = atomicAdd(&cursor[d], 1);
            src_sorted[pos] = src[e];
        }
    }
}

// ---------------- aggregation: one wave per dst node, 8 edges per iteration ----------------
// lane = 32*half + idx; idx covers channels idx*4..+3 (head = idx>>3).
// half handles edges k+4*half+u, u=0..3: 4 independent gathers in flight per lane
// (the gather path is line-request-throughput bound -> keep many lines outstanding).
__global__ __launch_bounds__(256) void agg_k(const unsigned* __restrict__ xlb,
                                             const unsigned* __restrict__ xrb,
                                             const float* __restrict__ att,
                                             const float* __restrict__ bias,
                                             const int* __restrict__ row_start,
                                             const int* __restrict__ src_sorted,
                                             int n, float* __restrict__ out) {
    const int wave = threadIdx.x >> 6;
    const int lane = threadIdx.x & 63;
    const int i = blockIdx.x * 4 + wave;
    if (i >= n) return;

    const int idx  = lane & 31;
    const int half = lane >> 5;

    uint2 xr2 = *(const uint2*)(xrb + (size_t)i * 64 + idx * 2);
    float xr0 = bf2f(xr2.x & 0xffffu), xr1 = bf2f(xr2.x >> 16);
    float xr2f = bf2f(xr2.y & 0xffffu), xr3 = bf2f(xr2.y >> 16);
    float4 at4 = *(const float4*)(att + idx * 4);

    const int k0 = row_start[i];
    const int k1 = row_start[i + 1];

    float l = 0.f, A0 = 0.f, A1 = 0.f, A2 = 0.f, A3 = 0.f;

    for (int k = k0; k < k1; k += 8) {
        const int kb = k + 4 * half;
        int s[4];
#pragma unroll
        for (int u = 0; u < 4; ++u) s[u] = src_sorted[kb + u];   // pad keeps reads in-bounds
        uint2 v[4];
#pragma unroll
        for (int u = 0; u < 4; ++u) v[u] = *(const uint2*)(xlb + (size_t)s[u] * 64 + idx * 2);
#pragma unroll
        for (int u = 0; u < 4; ++u) {
            float x0 = bf2f(v[u].x & 0xffffu), x1 = bf2f(v[u].x >> 16);
            float x2 = bf2f(v[u].y & 0xffffu), x3 = bf2f(v[u].y >> 16);
            float h0 = x0 + xr0, h1 = x1 + xr1, h2 = x2 + xr2f, h3 = x3 + xr3;
            h0 = fmaxf(h0, NEG_SLOPE * h0);
            h1 = fmaxf(h1, NEG_SLOPE * h1);
            h2 = fmaxf(h2, NEG_SLOPE * h2);
            h3 = fmaxf(h3, NEG_SLOPE * h3);
            float p = fmaf(at4.x, h0, at4.y * h1) + fmaf(at4.z, h2, at4.w * h3);
            p += __shfl_xor(p, 1);
            p += __shfl_xor(p, 2);
            p += __shfl_xor(p, 4);
            float w = (kb + u < k1) ? __expf(p) : 0.f;
            l += w;
            A0 = fmaf(w, x0, A0);
            A1 = fmaf(w, x1, A1);
            A2 = fmaf(w, x2, A2);
            A3 = fmaf(w, x3, A3);
        }
    }

    // merge the two halves
    l  += __shfl_xor(l, 32);
    A0 += __shfl_xor(A0, 32);
    A1 += __shfl_xor(A1, 32);
    A2 += __shfl_xor(A2, 32);
    A3 += __shfl_xor(A3, 32);

    if (half == 0) {
        float inv = 1.f / (l + EPS_F);
        float4 b4 = *(const float4*)(bias + idx * 4);
        float4 o = {fmaf(A0, inv, b4.x), fmaf(A1, inv, b4.y),
                    fmaf(A2, inv, b4.z), fmaf(A3, inv, b4.w)};
        *(float4*)(out + (size_t)i * 128 + idx * 4) = o;
    }
}

// ---------------- launch ----------------
extern "C" void kernel_launch(void* const* d_in, const int* in_sizes, int n_in,
                              void* d_out, int out_size, void* d_ws, size_t ws_size,
                              hipStream_t stream) {
    const float* x    = (const float*)d_in[0];
    const int*   ei   = (const int*)d_in[1];
    const float* W_l  = (const float*)d_in[2];
    const float* W_r  = (const float*)d_in[3];
    const float* att  = (const float*)d_in[4];
    const float* bias = (const float*)d_in[5];
    float* out = (float*)d_out;

    const int N = in_sizes[0] / 128;
    const int E = in_sizes[1] / 2;
    const int* src = ei;
    const int* dst = ei + E;

    char* ws = (char*)d_ws;
    size_t off = 0;
    auto alloc = [&](size_t bytes) {
        void* p = ws + off;
        off += (bytes + 15) & ~(size_t)15;
        return p;
    };
    unsigned* xlb     = (unsigned*)alloc((size_t)N * 64 * 4);   // bf16-packed
    unsigned* xrb     = (unsigned*)alloc((size_t)N * 64 * 4);
    int* cnt          = (int*)alloc((size_t)N * 4);
    int* row_start    = (int*)alloc((size_t)(N + 1) * 4);
    int* cursor       = (int*)alloc((size_t)N * 4);
    const int nsb = (N + SCAN_B - 1) / SCAN_B;
    int* bsum         = (int*)alloc((size_t)nsb * 4);
    int* src_sorted   = (int*)alloc((size_t)(E + 8) * 4);
    (void)ws_size;

    hipMemsetAsync(cnt, 0, (size_t)N * 4, stream);

    const int rsz = (N + NRANGE - 1) / NRANGE;
    const int nchunks = 128;
    const int chunk_e = (E + nchunks - 1) / nchunks;
    const int nHist = NRANGE * nchunks;                 // 1024 hist blocks first
    const int gB = (N + 63) / 64;
    gemm_hist_k<<<nHist + gB, 256, 0, stream>>>(x, W_l, W_r, xlb, xrb, N,
                                                dst, E, rsz, chunk_e, nHist, cnt);

    scanA_k<<<nsb, SCAN_B, 0, stream>>>(cnt, N, row_start, bsum);
    scanB_k<<<1, 512, 0, stream>>>(bsum, nsb);
    scanC_k<<<nsb, SCAN_B, 0, stream>>>(row_start, bsum, cursor, N, E, src_sorted);

    scatter_k<<<NRANGE * nchunks, 256, 0, stream>>>(src, dst, E, rsz, chunk_e,
                                                    cursor, src_sorted);

    agg_k<<<(N + 3) / 4, 256, 0, stream>>>(xlb, xrb, att, bias, row_start, src_sorted, N, out);
}

// Round 6
// 368.473 us; speedup vs baseline: 1.2514x; 1.0848x over previous
//
#include <hip/hip_runtime.h>
#include <hip/hip_bf16.h>
#include <cstdint>
#include <cstddef>

// GATv2Conv forward, N=100000, E=1.6M, IN=128, H=4, C=32 (H*C=128).
//
// Pipeline:
//   1) prep_hist_k : blocks [0,nHist) = XCD-range-partitioned histogram of dst;
//                    block nHist = transpose+bf16-convert W_l,W_r -> Wt[n][k].
//   2) mfma_gemm_k : xl = x@W_l, xr = x@W_r via v_mfma_f32_16x16x32_bf16.
//                    64-row tiles; x fp32->bf16 staged in LDS (padded rows);
//                    B-frags = contiguous 16B ds_read from Wt; A-frags reused
//                    across both weight matrices. bf16 outputs.
//   3) scanA/B/C   : 2-level exclusive scan -> row_start/cursor (+pad src_sorted).
//   4) scatter_k   : XCD-range-partitioned counting-sort scatter.
//   5) agg_k       : one wave per dst node, 8 edges/iter, softmax w/o max-sub.

#define NEG_SLOPE 0.2f
#define EPS_F 1e-16f
#define NRANGE 8

typedef __attribute__((ext_vector_type(8))) short bf16x8;
typedef __attribute__((ext_vector_type(4))) float f32x4;

static __device__ __forceinline__ unsigned f2bf(float f) {
    unsigned u = __float_as_uint(f);
    return (u + 0x7fffu + ((u >> 16) & 1u)) >> 16;   // RNE
}
static __device__ __forceinline__ float bf2f(unsigned h) {
    return __uint_as_float(h << 16);
}

// ------------- prep: XCD-partitioned hist + W transpose/convert -------------
__global__ __launch_bounds__(256) void prep_hist_k(const int* __restrict__ dst, int E,
                                                   int rsz, int chunk_e, int nHist,
                                                   int* __restrict__ cnt,
                                                   const float* __restrict__ Wl,
                                                   const float* __restrict__ Wr,
                                                   unsigned short* __restrict__ Wtl,
                                                   unsigned short* __restrict__ Wtr) {
    if (blockIdx.x == (unsigned)nHist) {
        // W[k][n] fp32 -> Wt[n][k] bf16 (both matrices); 16384 elems each
        for (int mat = 0; mat < 2; ++mat) {
            const float* W = mat ? Wr : Wl;
            unsigned short* Wt = mat ? Wtr : Wtl;
            for (int i = 0; i < 64; ++i) {
                int idx = (int)threadIdx.x + i * 256;
                int k = idx >> 7, n = idx & 127;
                Wt[n * 128 + k] = (unsigned short)f2bf(W[idx]);
            }
        }
        return;
    }
    const int r = blockIdx.x & (NRANGE - 1);
    const int c = blockIdx.x >> 3;
    const unsigned r_lo = (unsigned)(r * rsz);
    const int e0 = c * chunk_e;
    const int e1 = min(e0 + chunk_e, E);
    for (int e = e0 + (int)threadIdx.x; e < e1; e += 256) {
        int d = dst[e];
        if ((unsigned)d - r_lo < (unsigned)rsz) atomicAdd(&cnt[d], 1);
    }
}

// ------------- MFMA GEMM: xl = x@Wl, xr = x@Wr (bf16 in, bf16 out) -------------
// Block = 256 thr = 4 waves, 64 rows. Wave w: rows w*16..w*16+15, all 128 cols.
// A-frag: A[m=lane&15][k=quad*8+j]; B-frag: B(k)[n=lane&15][k=quad*8+j] from Wt;
// C/D: [row=quad*4+reg][col=lane&15]  (m89/m91-verified layouts).
#define LROW 136   // 128 + 8 ushort pad: row stride 272B -> 2-way max bank aliasing
__global__ __launch_bounds__(256) void mfma_gemm_k(const float* __restrict__ A,
                                                   const unsigned short* __restrict__ Wtl,
                                                   const unsigned short* __restrict__ Wtr,
                                                   unsigned short* __restrict__ xl,
                                                   unsigned short* __restrict__ xr,
                                                   int nrows) {
    __shared__ unsigned short As[64 * LROW];    // 17.0 KB
    __shared__ unsigned short Ws[128 * LROW];   // 34.0 KB
    const int tid = threadIdx.x;
    const int wave = tid >> 6, lane = tid & 63;
    const int quad = lane >> 4, m16 = lane & 15;
    const int row0 = blockIdx.x * 64;

    // stage A: 64 rows x 128 k, fp32 -> bf16 (2048 float4, 8/thread)
#pragma unroll
    for (int i = 0; i < 8; ++i) {
        int idx = tid + i * 256;
        int r = idx >> 5, c4 = idx & 31;
        int gr = row0 + r;
        gr = gr < nrows ? gr : nrows - 1;
        float4 v = *(const float4*)(A + (size_t)gr * 128 + c4 * 4);
        ushort4 b;
        b.x = (unsigned short)f2bf(v.x);
        b.y = (unsigned short)f2bf(v.y);
        b.z = (unsigned short)f2bf(v.z);
        b.w = (unsigned short)f2bf(v.w);
        *(ushort4*)(&As[r * LROW + c4 * 4]) = b;
    }
    // stage Wt_l: 128 n x 128 k bf16 (2048 uint4, 8/thread)
#pragma unroll
    for (int i = 0; i < 8; ++i) {
        int idx = tid + i * 256;
        int n = idx >> 4, kq = idx & 15;
        *(uint4*)(&Ws[n * LROW + kq * 8]) = *(const uint4*)(Wtl + n * 128 + kq * 8);
    }
    __syncthreads();

    // A-frags: 4 k-steps, held across both matrices
    bf16x8 af[4];
#pragma unroll
    for (int ks = 0; ks < 4; ++ks)
        af[ks] = *(const bf16x8*)(&As[(wave * 16 + m16) * LROW + ks * 32 + quad * 8]);

    f32x4 acc[8];
#pragma unroll
    for (int ct = 0; ct < 8; ++ct) acc[ct] = (f32x4){0.f, 0.f, 0.f, 0.f};
#pragma unroll
    for (int ct = 0; ct < 8; ++ct)
#pragma unroll
        for (int ks = 0; ks < 4; ++ks) {
            bf16x8 bf = *(const bf16x8*)(&Ws[(ct * 16 + m16) * LROW + ks * 32 + quad * 8]);
            acc[ct] = __builtin_amdgcn_mfma_f32_16x16x32_bf16(af[ks], bf, acc[ct], 0, 0, 0);
        }
#pragma unroll
    for (int ct = 0; ct < 8; ++ct)
#pragma unroll
        for (int r = 0; r < 4; ++r) {
            int grow = row0 + wave * 16 + quad * 4 + r;
            if (grow < nrows) xl[(size_t)grow * 128 + ct * 16 + m16] = (unsigned short)f2bf(acc[ct][r]);
        }

    __syncthreads();   // done reading Ws
    // stage Wt_r into the same buffer
#pragma unroll
    for (int i = 0; i < 8; ++i) {
        int idx = tid + i * 256;
        int n = idx >> 4, kq = idx & 15;
        *(uint4*)(&Ws[n * LROW + kq * 8]) = *(const uint4*)(Wtr + n * 128 + kq * 8);
    }
    __syncthreads();

#pragma unroll
    for (int ct = 0; ct < 8; ++ct) acc[ct] = (f32x4){0.f, 0.f, 0.f, 0.f};
#pragma unroll
    for (int ct = 0; ct < 8; ++ct)
#pragma unroll
        for (int ks = 0; ks < 4; ++ks) {
            bf16x8 bf = *(const bf16x8*)(&Ws[(ct * 16 + m16) * LROW + ks * 32 + quad * 8]);
            acc[ct] = __builtin_amdgcn_mfma_f32_16x16x32_bf16(af[ks], bf, acc[ct], 0, 0, 0);
        }
#pragma unroll
    for (int ct = 0; ct < 8; ++ct)
#pragma unroll
        for (int r = 0; r < 4; ++r) {
            int grow = row0 + wave * 16 + quad * 4 + r;
            if (grow < nrows) xr[(size_t)grow * 128 + ct * 16 + m16] = (unsigned short)f2bf(acc[ct][r]);
        }
}

// ---------------- 2-level scan ----------------
#define SCAN_B 256
__global__ __launch_bounds__(SCAN_B) void scanA_k(const int* __restrict__ cnt, int n,
                                                  int* __restrict__ row_start,
                                                  int* __restrict__ bsum) {
    const int tid = threadIdx.x, lane = tid & 63, wid = tid >> 6;
    const int g = blockIdx.x * SCAN_B + tid;
    int v = (g < n) ? cnt[g] : 0;
    int inc = v;
#pragma unroll
    for (int d = 1; d < 64; d <<= 1) {
        int t = __shfl_up(inc, d);
        if (lane >= d) inc += t;
    }
    __shared__ int wsum[SCAN_B / 64];
    if (lane == 63) wsum[wid] = inc;
    __syncthreads();
    int add = 0;
    for (int w = 0; w < wid; ++w) add += wsum[w];
    inc += add;
    if (g < n) row_start[g] = inc - v;
    if (tid == SCAN_B - 1) bsum[blockIdx.x] = inc;
}

__global__ __launch_bounds__(512) void scanB_k(int* __restrict__ bsum, int nb) {
    const int tid = threadIdx.x, lane = tid & 63, wid = tid >> 6;
    int v = (tid < nb) ? bsum[tid] : 0;
    int inc = v;
#pragma unroll
    for (int d = 1; d < 64; d <<= 1) {
        int t = __shfl_up(inc, d);
        if (lane >= d) inc += t;
    }
    __shared__ int wsum[8];
    if (lane == 63) wsum[wid] = inc;
    __syncthreads();
    int add = 0;
    for (int w = 0; w < wid; ++w) add += wsum[w];
    inc += add;
    if (tid < nb) bsum[tid] = inc - v;
}

__global__ __launch_bounds__(SCAN_B) void scanC_k(int* __restrict__ row_start,
                                                  const int* __restrict__ bsum,
                                                  int* __restrict__ cursor, int n, int E,
                                                  int* __restrict__ src_sorted) {
    const int g = blockIdx.x * SCAN_B + threadIdx.x;
    if (g < n) {
        int v = row_start[g] + bsum[blockIdx.x];
        row_start[g] = v;
        cursor[g] = v;
    }
    if (g == 0) row_start[n] = E;
    if (blockIdx.x == 0 && threadIdx.x < 8) src_sorted[E + threadIdx.x] = 0;
}

// XCD-range-partitioned scatter.
__global__ __launch_bounds__(256) void scatter_k(const int* __restrict__ src,
                                                 const int* __restrict__ dst, int E,
                                                 int rsz, int chunk_e,
                                                 int* __restrict__ cursor,
                                                 int* __restrict__ src_sorted) {
    const int r = blockIdx.x & (NRANGE - 1);
    const int c = blockIdx.x >> 3;
    const unsigned r_lo = (unsigned)(r * rsz);
    const int e0 = c * chunk_e;
    const int e1 = min(e0 + chunk_e, E);
    for (int e = e0 + (int)threadIdx.x; e < e1; e += 256) {
        int d = dst[e];
        if ((unsigned)d - r_lo < (unsigned)rsz) {
            int pos = atomicAdd(&cursor[d], 1);
            src_sorted[pos] = src[e];
        }
    }
}

// ---------------- aggregation: one wave per dst node, 8 edges per iteration ----------------
__global__ __launch_bounds__(256) void agg_k(const unsigned* __restrict__ xlb,
                                             const unsigned* __restrict__ xrb,
                                             const float* __restrict__ att,
                                             const float* __restrict__ bias,
                                             const int* __restrict__ row_start,
                                             const int* __restrict__ src_sorted,
                                             int n, float* __restrict__ out) {
    const int wave = threadIdx.x >> 6;
    const int lane = threadIdx.x & 63;
    const int i = blockIdx.x * 4 + wave;
    if (i >= n) return;

    const int idx  = lane & 31;
    const int half = lane >> 5;

    uint2 xr2 = *(const uint2*)(xrb + (size_t)i * 64 + idx * 2);
    float xr0 = bf2f(xr2.x & 0xffffu), xr1 = bf2f(xr2.x >> 16);
    float xr2f = bf2f(xr2.y & 0xffffu), xr3 = bf2f(xr2.y >> 16);
    float4 at4 = *(const float4*)(att + idx * 4);

    const int k0 = row_start[i];
    const int k1 = row_start[i + 1];

    float l = 0.f, A0 = 0.f, A1 = 0.f, A2 = 0.f, A3 = 0.f;

    for (int k = k0; k < k1; k += 8) {
        const int kb = k + 4 * half;
        int s[4];
#pragma unroll
        for (int u = 0; u < 4; ++u) s[u] = src_sorted[kb + u];
        uint2 v[4];
#pragma unroll
        for (int u = 0; u < 4; ++u) v[u] = *(const uint2*)(xlb + (size_t)s[u] * 64 + idx * 2);
#pragma unroll
        for (int u = 0; u < 4; ++u) {
            float x0 = bf2f(v[u].x & 0xffffu), x1 = bf2f(v[u].x >> 16);
            float x2 = bf2f(v[u].y & 0xffffu), x3 = bf2f(v[u].y >> 16);
            float h0 = x0 + xr0, h1 = x1 + xr1, h2 = x2 + xr2f, h3 = x3 + xr3;
            h0 = fmaxf(h0, NEG_SLOPE * h0);
            h1 = fmaxf(h1, NEG_SLOPE * h1);
            h2 = fmaxf(h2, NEG_SLOPE * h2);
            h3 = fmaxf(h3, NEG_SLOPE * h3);
            float p = fmaf(at4.x, h0, at4.y * h1) + fmaf(at4.z, h2, at4.w * h3);
            p += __shfl_xor(p, 1);
            p += __shfl_xor(p, 2);
            p += __shfl_xor(p, 4);
            float w = (kb + u < k1) ? __expf(p) : 0.f;
            l += w;
            A0 = fmaf(w, x0, A0);
            A1 = fmaf(w, x1, A1);
            A2 = fmaf(w, x2, A2);
            A3 = fmaf(w, x3, A3);
        }
    }

    l  += __shfl_xor(l, 32);
    A0 += __shfl_xor(A0, 32);
    A1 += __shfl_xor(A1, 32);
    A2 += __shfl_xor(A2, 32);
    A3 += __shfl_xor(A3, 32);

    if (half == 0) {
        float inv = 1.f / (l + EPS_F);
        float4 b4 = *(const float4*)(bias + idx * 4);
        float4 o = {fmaf(A0, inv, b4.x), fmaf(A1, inv, b4.y),
                    fmaf(A2, inv, b4.z), fmaf(A3, inv, b4.w)};
        *(float4*)(out + (size_t)i * 128 + idx * 4) = o;
    }
}

// ---------------- launch ----------------
extern "C" void kernel_launch(void* const* d_in, const int* in_sizes, int n_in,
                              void* d_out, int out_size, void* d_ws, size_t ws_size,
                              hipStream_t stream) {
    const float* x    = (const float*)d_in[0];
    const int*   ei   = (const int*)d_in[1];
    const float* W_l  = (const float*)d_in[2];
    const float* W_r  = (const float*)d_in[3];
    const float* att  = (const float*)d_in[4];
    const float* bias = (const float*)d_in[5];
    float* out = (float*)d_out;

    const int N = in_sizes[0] / 128;
    const int E = in_sizes[1] / 2;
    const int* src = ei;
    const int* dst = ei + E;

    char* ws = (char*)d_ws;
    size_t off = 0;
    auto alloc = [&](size_t bytes) {
        void* p = ws + off;
        off += (bytes + 15) & ~(size_t)15;
        return p;
    };
    unsigned* xlb     = (unsigned*)alloc((size_t)N * 64 * 4);   // bf16-packed [N][128]
    unsigned* xrb     = (unsigned*)alloc((size_t)N * 64 * 4);
    int* cnt          = (int*)alloc((size_t)N * 4);
    int* row_start    = (int*)alloc((size_t)(N + 1) * 4);
    int* cursor       = (int*)alloc((size_t)N * 4);
    const int nsb = (N + SCAN_B - 1) / SCAN_B;
    int* bsum         = (int*)alloc((size_t)nsb * 4);
    int* src_sorted   = (int*)alloc((size_t)(E + 8) * 4);
    unsigned short* Wtl = (unsigned short*)alloc((size_t)128 * 128 * 2);
    unsigned short* Wtr = (unsigned short*)alloc((size_t)128 * 128 * 2);
    (void)ws_size;

    hipMemsetAsync(cnt, 0, (size_t)N * 4, stream);

    const int rsz = (N + NRANGE - 1) / NRANGE;
    const int nchunks = 128;
    const int chunk_e = (E + nchunks - 1) / nchunks;
    const int nHist = NRANGE * nchunks;                 // 1024 hist blocks + 1 transpose
    prep_hist_k<<<nHist + 1, 256, 0, stream>>>(dst, E, rsz, chunk_e, nHist, cnt,
                                               W_l, W_r, Wtl, Wtr);

    const int gB = (N + 63) / 64;
    mfma_gemm_k<<<gB, 256, 0, stream>>>(x, Wtl, Wtr,
                                        (unsigned short*)xlb, (unsigned short*)xrb, N);

    scanA_k<<<nsb, SCAN_B, 0, stream>>>(cnt, N, row_start, bsum);
    scanB_k<<<1, 512, 0, stream>>>(bsum, nsb);
    scanC_k<<<nsb, SCAN_B, 0, stream>>>(row_start, bsum, cursor, N, E, src_sorted);

    scatter_k<<<NRANGE * nchunks, 256, 0, stream>>>(src, dst, E, rsz, chunk_e,
                                                    cursor, src_sorted);

    agg_k<<<(N + 3) / 4, 256, 0, stream>>>(xlb, xrb, att, bias, row_start, src_sorted, N, out);
}